// Round 18
// baseline (110.581 us; speedup 1.0000x reference)
//
#include <hip/hip_runtime.h>
#include <hip/hip_bf16.h>
#include <stdint.h>

#define B_    4
#define H_    16
#define L_    2048
#define D_    64
#define BH_   64
#define NT_   32
#define MASKBIAS (-1.4426950408889634e9f)   // -1e9 * log2(e), exp2-domain

typedef __attribute__((ext_vector_type(8))) short bf16x8;
typedef __attribute__((ext_vector_type(8))) unsigned short ushort8;
typedef __attribute__((ext_vector_type(4))) unsigned short ushort4v;
typedef __attribute__((ext_vector_type(4))) float f32x4;

__device__ __forceinline__ ushort f2bf(float f) {
  union { float f; uint32_t u; } x; x.f = f;
  uint32_t r = x.u + 0x7FFFu + ((x.u >> 16) & 1u);
  return (ushort)(r >> 16);
}

__device__ __forceinline__ uint32_t pkbf(float lo, float hi) {
  uint32_t r;
  asm("v_cvt_pk_bf16_f32 %0, %1, %2" : "=v"(r) : "v"(lo), "v"(hi));
  return r;
}

// ---------------- pre-pass: fp32 -> bf16, tiled + permuted + swizzled + mask bias ----------------
// Kp tile (bh,kt): elem(row,d) at row*64 + (d ^ ((row&7)<<3))
// Vtp tile: elem(d,pos) at d*64 + (pos ^ ((d&7)<<3)), holding V[k(pos)][d],
//   pos = 32c+8lg+4b+a  <->  k = 32c+16b+4lg+a  (MFMA A-frag slot order)
// Mb[b][k] = 0.0f (keep) or MASKBIAS (drop)
__global__ __launch_bounds__(256, 2)
void prep_kv(const float* __restrict__ K, const float* __restrict__ V,
             const int* __restrict__ Mask,
             ushort* __restrict__ Kp, ushort* __restrict__ Vtp,
             float* __restrict__ Mb)
{
  __shared__ ushort Vl[64 * 68];
  const int bid = blockIdx.x;      // bh*32 + kt
  const int tid = threadIdx.x;
  const float* Kg = K + (size_t)bid * 4096;
  const float* Vg = V + (size_t)bid * 4096;
  ushort* Kt = Kp + (size_t)bid * 4096;
  ushort* Vt = Vtp + (size_t)bid * 4096;

#pragma unroll
  for (int j = 0; j < 2; ++j) {
    int chunk = j * 256 + tid;
    int row = chunk >> 3, d8 = chunk & 7;
    const float* s = Kg + row * 64 + d8 * 8;
    float4 a = *(const float4*)s, b2 = *(const float4*)(s + 4);
    ushort8 o;
    o[0]=f2bf(a.x); o[1]=f2bf(a.y); o[2]=f2bf(a.z); o[3]=f2bf(a.w);
    o[4]=f2bf(b2.x);o[5]=f2bf(b2.y);o[6]=f2bf(b2.z);o[7]=f2bf(b2.w);
    *(ushort8*)(Kt + row * 64 + ((d8 * 8) ^ ((row & 7) << 3))) = o;

    const float* sv = Vg + row * 64 + d8 * 8;
    float4 va = *(const float4*)sv, vb2 = *(const float4*)(sv + 4);
    ushort4v w0, w1;
    w0[0]=f2bf(va.x); w0[1]=f2bf(va.y); w0[2]=f2bf(va.z); w0[3]=f2bf(va.w);
    w1[0]=f2bf(vb2.x);w1[1]=f2bf(vb2.y);w1[2]=f2bf(vb2.z);w1[3]=f2bf(vb2.w);
    *(ushort4v*)(&Vl[row * 68 + d8 * 8])     = w0;
    *(ushort4v*)(&Vl[row * 68 + d8 * 8 + 4]) = w1;
  }
  __syncthreads();
#pragma unroll
  for (int j = 0; j < 2; ++j) {
    int chunk = j * 256 + tid;
    int d = chunk >> 3, p8 = chunk & 7;
    ushort8 o;
#pragma unroll
    for (int e = 0; e < 8; ++e) {
      int pos = p8 * 8 + e;
      int c = pos >> 5, lgv = (pos >> 3) & 3, bb = (pos >> 2) & 1, aa = pos & 3;
      int kk = 32 * c + 16 * bb + 4 * lgv + aa;
      o[e] = Vl[kk * 68 + d];
    }
    *(ushort8*)(Vt + d * 64 + ((p8 * 8) ^ ((d & 7) << 3))) = o;
  }
  if ((((bid >> 5) & 15) == 0) && tid < 64) {
    int b = bid >> 9, kt = bid & 31;
    int idx = b * 2048 + kt * 64 + tid;
    Mb[idx] = (Mask[idx] != 0) ? 0.f : MASKBIAS;
  }
}

// ------- main attention: r16 pipeline, 2-wave blocks (4 blocks/CU, 4-phase stagger) -------
__global__ __launch_bounds__(128, 2)
void attn_fwd18(const float* __restrict__ Q, const float* __restrict__ Mb,
                const ushort* __restrict__ Kp, const ushort* __restrict__ Vtp,
                float* __restrict__ O)
{
  __shared__ __align__(16) ushort Kb[2][4096];
  __shared__ __align__(16) ushort Vb[2][4096];

  const int tid  = threadIdx.x;        // 0..127
  const int wid  = tid >> 6;           // 0..1
  const int lane = tid & 63;
  const int lr   = lane & 15;
  const int lg   = lane >> 4;

  // XCD-aware mapping: 128 contiguous logical blocks per XCD -> 8 bh per XCD
  const int x   = blockIdx.x;          // 0..1023
  const int lin = (x & 7) * 128 + (x >> 3);
  const int bh  = lin >> 4;            // 0..63
  const int qt  = lin & 15;            // 0..15
  const int b   = bh >> 4;

  // de-phase the 4 co-resident dispatch rounds by 8 KV-tiles each
  const int phase = ((x >> 8) & 3) << 3;

  const float*  Qg    = Q + (size_t)bh * L_ * D_;
  float*        Og    = O + (size_t)bh * L_ * D_;
  const ushort* Kbase = Kp  + (size_t)bh * 131072;
  const ushort* Vbase = Vtp + (size_t)bh * 131072;
  const float*  Mbb   = Mb + (size_t)b * L_;

  const int qbase = qt * 128 + wid * 64;
  const float qscale = 0.125f * 1.4426950408889634f;  // scale * log2(e)

  // ---- Q fragments (scaled, bf16, persistent): 4 row-groups ----
  bf16x8 qf[4][2];
#pragma unroll
  for (int g = 0; g < 4; ++g)
#pragma unroll
    for (int c = 0; c < 2; ++c) {
      const float* src = Qg + (size_t)(qbase + g * 16 + lr) * D_ + c * 32 + lg * 8;
      float4 a = *(const float4*)src, b2 = *(const float4*)(src + 4);
      bf16x8 q;
      q[0]=f2bf(a.x*qscale);  q[1]=f2bf(a.y*qscale);  q[2]=f2bf(a.z*qscale);  q[3]=f2bf(a.w*qscale);
      q[4]=f2bf(b2.x*qscale); q[5]=f2bf(b2.y*qscale); q[6]=f2bf(b2.z*qscale); q[7]=f2bf(b2.w*qscale);
      qf[g][c] = q;
    }

  f32x4 o_acc[4][4];
#pragma unroll
  for (int g = 0; g < 4; ++g)
#pragma unroll
    for (int dt = 0; dt < 4; ++dt) o_acc[g][dt] = (f32x4){0.f,0.f,0.f,0.f};
  f32x4 l_mf[4];
#pragma unroll
  for (int g = 0; g < 4; ++g) l_mf[g] = (f32x4){0.f,0.f,0.f,0.f};

  bf16x8 vone;
#pragma unroll
  for (int i = 0; i < 8; ++i) vone[i] = (short)0x3F80;  // bf16 1.0

  // persistent pipeline registers: previous tile's packed P and V fragments
  union PKU { uint32_t u[8]; bf16x8 v[2]; };
  PKU    pkp[4];
  bf16x8 vbp[4][2];

  // ---- staging prologue: tile `phase` -> regs (4 chunks/thread = full 4096-ushort tile) ----
  int kts = phase;
  ushort8 rk[4], rv[4];
#pragma unroll
  for (int j = 0; j < 4; ++j) {
    rk[j] = *(const ushort8*)(Kbase + (size_t)kts * 4096 + j * 1024 + wid * 512 + lane * 8);
    rv[j] = *(const ushort8*)(Vbase + (size_t)kts * 4096 + j * 1024 + wid * 512 + lane * 8);
  }

  int cur = 0;
  for (int kt = 0; kt < NT_; ++kt) {
    // publish staged regs -> buf[cur]  (full tile: j*1024 + wid*512 + lane*8 covers [0,4096))
#pragma unroll
    for (int j = 0; j < 4; ++j) {
      *(ushort8*)(&Kb[cur][j * 1024 + wid * 512 + lane * 8]) = rk[j];
      *(ushort8*)(&Vb[cur][j * 1024 + wid * 512 + lane * 8]) = rv[j];
    }

    __syncthreads();   // 2-wave barrier (cheap)

    // issue next tile's global loads (fly across full compute phase)
    const int knx = (kts + 1) & 31;
    {
      const ushort* Ks = Kbase + (size_t)knx * 4096;
      const ushort* Vs = Vbase + (size_t)knx * 4096;
#pragma unroll
      for (int j = 0; j < 4; ++j) {
        rk[j] = *(const ushort8*)(Ks + j * 1024 + wid * 512 + lane * 8);
        rv[j] = *(const ushort8*)(Vs + j * 1024 + wid * 512 + lane * 8);
      }
    }

    // mask bias (global, L2-hot) — latency covered by PV(prev) below
    f32x4 bt[4];
#pragma unroll
    for (int t = 0; t < 4; ++t) bt[t] = *(const f32x4*)(Mbb + kts * 64 + 16 * t + 4 * lg);

    const ushort* Kc = Kb[cur];
    const ushort* Vc = Vb[cur];

    // K fragment ds_reads (latency covered by PV(prev))
    bf16x8 kf[4][2];
#pragma unroll
    for (int t = 0; t < 4; ++t)
#pragma unroll
      for (int c = 0; c < 2; ++c)
        kf[t][c] = *(const bf16x8*)(Kc + (16 * t + lr) * 64 + ((c * 32 + lg * 8) ^ ((lr & 7) << 3)));

    // ---- PV + l of PREVIOUS tile: all operands in registers ----
    if (kt > 0) {
      __builtin_amdgcn_s_setprio(1);
#pragma unroll
      for (int g = 0; g < 4; ++g) {
        l_mf[g] = __builtin_amdgcn_mfma_f32_16x16x32_bf16(pkp[g].v[0], vone, l_mf[g], 0, 0, 0);
        l_mf[g] = __builtin_amdgcn_mfma_f32_16x16x32_bf16(pkp[g].v[1], vone, l_mf[g], 0, 0, 0);
      }
#pragma unroll
      for (int c = 0; c < 2; ++c)
#pragma unroll
        for (int dt = 0; dt < 4; ++dt)
#pragma unroll
          for (int g = 0; g < 4; ++g)
            o_acc[g][dt] = __builtin_amdgcn_mfma_f32_16x16x32_bf16(pkp[g].v[c], vbp[dt][c], o_acc[g][dt], 0, 0, 0);
      __builtin_amdgcn_s_setprio(0);
    }

    // V fragment ds_reads for THIS tile -> vbp (consumed next iter; huge slack)
#pragma unroll
    for (int dt = 0; dt < 4; ++dt)
#pragma unroll
      for (int c = 0; c < 2; ++c)
        vbp[dt][c] = *(const bf16x8*)(Vc + (16 * dt + lr) * 64 + ((c * 32 + lg * 8) ^ ((lr & 7) << 3)));

    // ---- QK^T (C-init=bias) -> exp2 -> pack into pkp (pkp free after PV above) ----
#pragma unroll
    for (int g = 0; g < 4; ++g) {
      f32x4 st[4];
      __builtin_amdgcn_s_setprio(1);
#pragma unroll
      for (int t = 0; t < 4; ++t)
        st[t] = __builtin_amdgcn_mfma_f32_16x16x32_bf16(kf[t][0], qf[g][0], bt[t], 0, 0, 0);
#pragma unroll
      for (int t = 0; t < 4; ++t)
        st[t] = __builtin_amdgcn_mfma_f32_16x16x32_bf16(kf[t][1], qf[g][1], st[t], 0, 0, 0);
      __builtin_amdgcn_s_setprio(0);

      f32x4 p0, p1, p2, p3;
#pragma unroll
      for (int r = 0; r < 4; ++r) {
        p0[r] = __builtin_amdgcn_exp2f(st[0][r]);
        p1[r] = __builtin_amdgcn_exp2f(st[1][r]);
        p2[r] = __builtin_amdgcn_exp2f(st[2][r]);
        p3[r] = __builtin_amdgcn_exp2f(st[3][r]);
      }
      pkp[g].u[0] = pkbf(p0[0], p0[1]); pkp[g].u[1] = pkbf(p0[2], p0[3]);
      pkp[g].u[2] = pkbf(p1[0], p1[1]); pkp[g].u[3] = pkbf(p1[2], p1[3]);
      pkp[g].u[4] = pkbf(p2[0], p2[1]); pkp[g].u[5] = pkbf(p2[2], p2[3]);
      pkp[g].u[6] = pkbf(p3[0], p3[1]); pkp[g].u[7] = pkbf(p3[2], p3[3]);
    }

    kts = knx;
    cur ^= 1;
  }

  // ---- final PV + l for the last tile ----
  __builtin_amdgcn_s_setprio(1);
#pragma unroll
  for (int g = 0; g < 4; ++g) {
    l_mf[g] = __builtin_amdgcn_mfma_f32_16x16x32_bf16(pkp[g].v[0], vone, l_mf[g], 0, 0, 0);
    l_mf[g] = __builtin_amdgcn_mfma_f32_16x16x32_bf16(pkp[g].v[1], vone, l_mf[g], 0, 0, 0);
  }
#pragma unroll
  for (int c = 0; c < 2; ++c)
#pragma unroll
    for (int dt = 0; dt < 4; ++dt)
#pragma unroll
      for (int g = 0; g < 4; ++g)
        o_acc[g][dt] = __builtin_amdgcn_mfma_f32_16x16x32_bf16(pkp[g].v[c], vbp[dt][c], o_acc[g][dt], 0, 0, 0);
  __builtin_amdgcn_s_setprio(0);

  // ---- epilogue: l_mf[g][r] already per-q (lane-replicated) ----
#pragma unroll
  for (int g = 0; g < 4; ++g) {
    float linv[4];
#pragma unroll
    for (int r = 0; r < 4; ++r) linv[r] = 1.0f / l_mf[g][r];
#pragma unroll
    for (int dt = 0; dt < 4; ++dt)
#pragma unroll
      for (int r = 0; r < 4; ++r) {
        int row = qbase + g * 16 + 4 * lg + r;
        Og[(size_t)row * D_ + dt * 16 + lr] = o_acc[g][dt][r] * linv[r];
      }
  }
}

extern "C" void kernel_launch(void* const* d_in, const int* in_sizes, int n_in,
                              void* d_out, int out_size, void* d_ws, size_t ws_size,
                              hipStream_t stream) {
  const float* Q = (const float*)d_in[0];
  const float* K = (const float*)d_in[1];
  const float* V = (const float*)d_in[2];
  const int*   M = (const int*)d_in[3];
  float*       O = (float*)d_out;

  const size_t elems = (size_t)BH_ * L_ * D_;   // 8,388,608
  ushort* Kp  = (ushort*)d_ws;
  ushort* Vtp = Kp + elems;
  float*  Mb  = (float*)(Vtp + elems);          // 4*2048 floats
  prep_kv<<<dim3(BH_ * NT_), dim3(256), 0, stream>>>(K, V, M, Kp, Vtp, Mb);
  attn_fwd18<<<dim3(1024), dim3(128), 0, stream>>>(Q, Mb, Kp, Vtp, O);
}

// Round 19
// 93.162 us; speedup vs baseline: 1.1870x; 1.1870x over previous
//
#include <hip/hip_runtime.h>
#include <hip/hip_bf16.h>
#include <stdint.h>

#define B_    4
#define H_    16
#define L_    2048
#define D_    64
#define BH_   64
#define NT_   32
#define MASKBIAS (-1.4426950408889634e9f)   // -1e9 * log2(e), exp2-domain

typedef __attribute__((ext_vector_type(8))) short bf16x8;
typedef __attribute__((ext_vector_type(8))) unsigned short ushort8;
typedef __attribute__((ext_vector_type(4))) unsigned short ushort4v;
typedef __attribute__((ext_vector_type(4))) float f32x4;

__device__ __forceinline__ ushort f2bf(float f) {
  union { float f; uint32_t u; } x; x.f = f;
  uint32_t r = x.u + 0x7FFFu + ((x.u >> 16) & 1u);
  return (ushort)(r >> 16);
}

__device__ __forceinline__ uint32_t pkbf(float lo, float hi) {
  uint32_t r;
  asm("v_cvt_pk_bf16_f32 %0, %1, %2" : "=v"(r) : "v"(lo), "v"(hi));
  return r;
}

// async global->LDS, 16B/lane. LDS dest = wave-uniform base + lane*16 (HW rule);
// global src is per-lane. Kp/Vtp are linear images of the LDS layout (rule #21 ok).
__device__ __forceinline__ void gload16(const ushort* g, ushort* l) {
  __builtin_amdgcn_global_load_lds(
      (const __attribute__((address_space(1))) uint32_t*)g,
      (__attribute__((address_space(3))) uint32_t*)l, 16, 0, 0);
}

// ---------------- pre-pass: fp32 -> bf16, tiled + permuted + swizzled + mask bias ----------------
__global__ __launch_bounds__(256, 2)
void prep_kv(const float* __restrict__ K, const float* __restrict__ V,
             const int* __restrict__ Mask,
             ushort* __restrict__ Kp, ushort* __restrict__ Vtp,
             float* __restrict__ Mb)
{
  __shared__ ushort Vl[64 * 68];
  const int bid = blockIdx.x;      // bh*32 + kt
  const int tid = threadIdx.x;
  const float* Kg = K + (size_t)bid * 4096;
  const float* Vg = V + (size_t)bid * 4096;
  ushort* Kt = Kp + (size_t)bid * 4096;
  ushort* Vt = Vtp + (size_t)bid * 4096;

#pragma unroll
  for (int j = 0; j < 2; ++j) {
    int chunk = j * 256 + tid;
    int row = chunk >> 3, d8 = chunk & 7;
    const float* s = Kg + row * 64 + d8 * 8;
    float4 a = *(const float4*)s, b2 = *(const float4*)(s + 4);
    ushort8 o;
    o[0]=f2bf(a.x); o[1]=f2bf(a.y); o[2]=f2bf(a.z); o[3]=f2bf(a.w);
    o[4]=f2bf(b2.x);o[5]=f2bf(b2.y);o[6]=f2bf(b2.z);o[7]=f2bf(b2.w);
    *(ushort8*)(Kt + row * 64 + ((d8 * 8) ^ ((row & 7) << 3))) = o;

    const float* sv = Vg + row * 64 + d8 * 8;
    float4 va = *(const float4*)sv, vb2 = *(const float4*)(sv + 4);
    ushort4v w0, w1;
    w0[0]=f2bf(va.x); w0[1]=f2bf(va.y); w0[2]=f2bf(va.z); w0[3]=f2bf(va.w);
    w1[0]=f2bf(vb2.x);w1[1]=f2bf(vb2.y);w1[2]=f2bf(vb2.z);w1[3]=f2bf(vb2.w);
    *(ushort4v*)(&Vl[row * 68 + d8 * 8])     = w0;
    *(ushort4v*)(&Vl[row * 68 + d8 * 8 + 4]) = w1;
  }
  __syncthreads();
#pragma unroll
  for (int j = 0; j < 2; ++j) {
    int chunk = j * 256 + tid;
    int d = chunk >> 3, p8 = chunk & 7;
    ushort8 o;
#pragma unroll
    for (int e = 0; e < 8; ++e) {
      int pos = p8 * 8 + e;
      int c = pos >> 5, lgv = (pos >> 3) & 3, bb = (pos >> 2) & 1, aa = pos & 3;
      int kk = 32 * c + 16 * bb + 4 * lgv + aa;
      o[e] = Vl[kk * 68 + d];
    }
    *(ushort8*)(Vt + d * 64 + ((p8 * 8) ^ ((d & 7) << 3))) = o;
  }
  if ((((bid >> 5) & 15) == 0) && tid < 64) {
    int b = bid >> 9, kt = bid & 31;
    int idx = b * 2048 + kt * 64 + tid;
    Mb[idx] = (Mask[idx] != 0) ? 0.f : MASKBIAS;
  }
}

// ------- main attention: 2-wave blocks (4/CU, 4-phase stagger), gload_lds staging,
//         rotated PV pipeline (r16) -------
__global__ __launch_bounds__(128, 2)
void attn_fwd19(const float* __restrict__ Q, const float* __restrict__ Mb,
                const ushort* __restrict__ Kp, const ushort* __restrict__ Vtp,
                float* __restrict__ O)
{
  __shared__ __align__(16) ushort Kb[2][4096];
  __shared__ __align__(16) ushort Vb[2][4096];

  const int tid  = threadIdx.x;        // 0..127
  const int wid  = tid >> 6;           // 0..1
  const int lane = tid & 63;
  const int lr   = lane & 15;
  const int lg   = lane >> 4;

  const int x   = blockIdx.x;          // 0..1023
  const int lin = (x & 7) * 128 + (x >> 3);
  const int bh  = lin >> 4;            // 0..63
  const int qt  = lin & 15;            // 0..15
  const int b   = bh >> 4;

  const int phase = ((x >> 8) & 3) << 3;   // 0/8/16/24

  const float*  Qg    = Q + (size_t)bh * L_ * D_;
  float*        Og    = O + (size_t)bh * L_ * D_;
  const ushort* Kbase = Kp  + (size_t)bh * 131072;
  const ushort* Vbase = Vtp + (size_t)bh * 131072;
  const float*  Mbb   = Mb + (size_t)b * L_;

  const int qbase = qt * 128 + wid * 64;
  const float qscale = 0.125f * 1.4426950408889634f;

  bf16x8 qf[4][2];
#pragma unroll
  for (int g = 0; g < 4; ++g)
#pragma unroll
    for (int c = 0; c < 2; ++c) {
      const float* src = Qg + (size_t)(qbase + g * 16 + lr) * D_ + c * 32 + lg * 8;
      float4 a = *(const float4*)src, b2 = *(const float4*)(src + 4);
      bf16x8 q;
      q[0]=f2bf(a.x*qscale);  q[1]=f2bf(a.y*qscale);  q[2]=f2bf(a.z*qscale);  q[3]=f2bf(a.w*qscale);
      q[4]=f2bf(b2.x*qscale); q[5]=f2bf(b2.y*qscale); q[6]=f2bf(b2.z*qscale); q[7]=f2bf(b2.w*qscale);
      qf[g][c] = q;
    }

  f32x4 o_acc[4][4];
#pragma unroll
  for (int g = 0; g < 4; ++g)
#pragma unroll
    for (int dt = 0; dt < 4; ++dt) o_acc[g][dt] = (f32x4){0.f,0.f,0.f,0.f};
  f32x4 l_mf[4];
#pragma unroll
  for (int g = 0; g < 4; ++g) l_mf[g] = (f32x4){0.f,0.f,0.f,0.f};

  bf16x8 vone;
#pragma unroll
  for (int i = 0; i < 8; ++i) vone[i] = (short)0x3F80;

  union PKU { uint32_t u[8]; bf16x8 v[2]; };
  PKU    pkp[4];
  bf16x8 vbp[4][2];

  // ---- prologue: async-stage tile `phase` -> buf 0 ----
  int kts = phase;
  {
    const ushort* Ks = Kbase + (size_t)kts * 4096;
    const ushort* Vs = Vbase + (size_t)kts * 4096;
#pragma unroll
    for (int j = 0; j < 4; ++j) {
      int off = j * 1024 + wid * 512;
      gload16(Ks + off + lane * 8, &Kb[0][off]);
      gload16(Vs + off + lane * 8, &Vb[0][off]);
    }
  }

  int cur = 0;
  for (int kt = 0; kt < NT_; ++kt) {
    // barrier: drains last iter's gloads (full-iteration slack) -> buf[cur] published
    __syncthreads();

    // async-stage NEXT tile -> buf[cur^1] (wrapped index; last-iter reload harmless)
    const int knx = (kts + 1) & 31;
    {
      const ushort* Ks = Kbase + (size_t)knx * 4096;
      const ushort* Vs = Vbase + (size_t)knx * 4096;
#pragma unroll
      for (int j = 0; j < 4; ++j) {
        int off = j * 1024 + wid * 512;
        gload16(Ks + off + lane * 8, &Kb[cur ^ 1][off]);
        gload16(Vs + off + lane * 8, &Vb[cur ^ 1][off]);
      }
    }

    f32x4 bt[4];
#pragma unroll
    for (int t = 0; t < 4; ++t) bt[t] = *(const f32x4*)(Mbb + kts * 64 + 16 * t + 4 * lg);

    const ushort* Kc = Kb[cur];
    const ushort* Vc = Vb[cur];

    bf16x8 kf[4][2];
#pragma unroll
    for (int t = 0; t < 4; ++t)
#pragma unroll
      for (int c = 0; c < 2; ++c)
        kf[t][c] = *(const bf16x8*)(Kc + (16 * t + lr) * 64 + ((c * 32 + lg * 8) ^ ((lr & 7) << 3)));

    // ---- PV + l of PREVIOUS tile (registers) ----
    if (kt > 0) {
      __builtin_amdgcn_s_setprio(1);
#pragma unroll
      for (int g = 0; g < 4; ++g) {
        l_mf[g] = __builtin_amdgcn_mfma_f32_16x16x32_bf16(pkp[g].v[0], vone, l_mf[g], 0, 0, 0);
        l_mf[g] = __builtin_amdgcn_mfma_f32_16x16x32_bf16(pkp[g].v[1], vone, l_mf[g], 0, 0, 0);
      }
#pragma unroll
      for (int c = 0; c < 2; ++c)
#pragma unroll
        for (int dt = 0; dt < 4; ++dt)
#pragma unroll
          for (int g = 0; g < 4; ++g)
            o_acc[g][dt] = __builtin_amdgcn_mfma_f32_16x16x32_bf16(pkp[g].v[c], vbp[dt][c], o_acc[g][dt], 0, 0, 0);
      __builtin_amdgcn_s_setprio(0);
    }

    // V fragments for THIS tile -> vbp (consumed next iter)
#pragma unroll
    for (int dt = 0; dt < 4; ++dt)
#pragma unroll
      for (int c = 0; c < 2; ++c)
        vbp[dt][c] = *(const bf16x8*)(Vc + (16 * dt + lr) * 64 + ((c * 32 + lg * 8) ^ ((lr & 7) << 3)));

    // ---- QK^T (C-init=bias) -> exp2 -> pack into pkp ----
#pragma unroll
    for (int g = 0; g < 4; ++g) {
      f32x4 st[4];
      __builtin_amdgcn_s_setprio(1);
#pragma unroll
      for (int t = 0; t < 4; ++t)
        st[t] = __builtin_amdgcn_mfma_f32_16x16x32_bf16(kf[t][0], qf[g][0], bt[t], 0, 0, 0);
#pragma unroll
      for (int t = 0; t < 4; ++t)
        st[t] = __builtin_amdgcn_mfma_f32_16x16x32_bf16(kf[t][1], qf[g][1], st[t], 0, 0, 0);
      __builtin_amdgcn_s_setprio(0);

      f32x4 p0, p1, p2, p3;
#pragma unroll
      for (int r = 0; r < 4; ++r) {
        p0[r] = __builtin_amdgcn_exp2f(st[0][r]);
        p1[r] = __builtin_amdgcn_exp2f(st[1][r]);
        p2[r] = __builtin_amdgcn_exp2f(st[2][r]);
        p3[r] = __builtin_amdgcn_exp2f(st[3][r]);
      }
      pkp[g].u[0] = pkbf(p0[0], p0[1]); pkp[g].u[1] = pkbf(p0[2], p0[3]);
      pkp[g].u[2] = pkbf(p1[0], p1[1]); pkp[g].u[3] = pkbf(p1[2], p1[3]);
      pkp[g].u[4] = pkbf(p2[0], p2[1]); pkp[g].u[5] = pkbf(p2[2], p2[3]);
      pkp[g].u[6] = pkbf(p3[0], p3[1]); pkp[g].u[7] = pkbf(p3[2], p3[3]);
    }

    kts = knx;
    cur ^= 1;
  }

  // ---- final PV + l for the last tile ----
  __builtin_amdgcn_s_setprio(1);
#pragma unroll
  for (int g = 0; g < 4; ++g) {
    l_mf[g] = __builtin_amdgcn_mfma_f32_16x16x32_bf16(pkp[g].v[0], vone, l_mf[g], 0, 0, 0);
    l_mf[g] = __builtin_amdgcn_mfma_f32_16x16x32_bf16(pkp[g].v[1], vone, l_mf[g], 0, 0, 0);
  }
#pragma unroll
  for (int c = 0; c < 2; ++c)
#pragma unroll
    for (int dt = 0; dt < 4; ++dt)
#pragma unroll
      for (int g = 0; g < 4; ++g)
        o_acc[g][dt] = __builtin_amdgcn_mfma_f32_16x16x32_bf16(pkp[g].v[c], vbp[dt][c], o_acc[g][dt], 0, 0, 0);
  __builtin_amdgcn_s_setprio(0);

  // ---- epilogue ----
#pragma unroll
  for (int g = 0; g < 4; ++g) {
    float linv[4];
#pragma unroll
    for (int r = 0; r < 4; ++r) linv[r] = 1.0f / l_mf[g][r];
#pragma unroll
    for (int dt = 0; dt < 4; ++dt)
#pragma unroll
      for (int r = 0; r < 4; ++r) {
        int row = qbase + g * 16 + 4 * lg + r;
        Og[(size_t)row * D_ + dt * 16 + lr] = o_acc[g][dt][r] * linv[r];
      }
  }
}

extern "C" void kernel_launch(void* const* d_in, const int* in_sizes, int n_in,
                              void* d_out, int out_size, void* d_ws, size_t ws_size,
                              hipStream_t stream) {
  const float* Q = (const float*)d_in[0];
  const float* K = (const float*)d_in[1];
  const float* V = (const float*)d_in[2];
  const int*   M = (const int*)d_in[3];
  float*       O = (float*)d_out;

  const size_t elems = (size_t)BH_ * L_ * D_;   // 8,388,608
  ushort* Kp  = (ushort*)d_ws;
  ushort* Vtp = Kp + elems;
  float*  Mb  = (float*)(Vtp + elems);          // 4*2048 floats
  prep_kv<<<dim3(BH_ * NT_), dim3(256), 0, stream>>>(K, V, M, Kp, Vtp, Mb);
  attn_fwd19<<<dim3(1024), dim3(128), 0, stream>>>(Q, Mb, Kp, Vtp, O);
}

// Round 20
// 91.886 us; speedup vs baseline: 1.2035x; 1.0139x over previous
//
#include <hip/hip_runtime.h>
#include <hip/hip_bf16.h>
#include <stdint.h>

#define B_    4
#define H_    16
#define L_    2048
#define D_    64
#define BH_   64
#define NT_   32
#define MASKBIAS (-1.4426950408889634e9f)   // -1e9 * log2(e), exp2-domain

typedef __attribute__((ext_vector_type(8))) short bf16x8;
typedef __attribute__((ext_vector_type(8))) unsigned short ushort8;
typedef __attribute__((ext_vector_type(4))) unsigned short ushort4v;
typedef __attribute__((ext_vector_type(4))) float f32x4;

__device__ __forceinline__ ushort f2bf(float f) {
  union { float f; uint32_t u; } x; x.f = f;
  uint32_t r = x.u + 0x7FFFu + ((x.u >> 16) & 1u);
  return (ushort)(r >> 16);
}

__device__ __forceinline__ uint32_t pkbf(float lo, float hi) {
  uint32_t r;
  asm("v_cvt_pk_bf16_f32 %0, %1, %2" : "=v"(r) : "v"(lo), "v"(hi));
  return r;
}

// ---------------- pre-pass: fp32 -> bf16, tiled + permuted + swizzled + mask bias ----------------
// Kp tile (bh,kt): elem(row,d) at row*64 + (d ^ ((row&7)<<3))
// Vtp tile: elem(d,pos) at d*64 + (pos ^ ((d&7)<<3)), holding V[k(pos)][d],
//   pos = 32c+8lg+4b+a  <->  k = 32c+16b+4lg+a  (MFMA A-frag slot order)
// Mb[b][k] = 0.0f (keep) or MASKBIAS (drop)
__global__ __launch_bounds__(256, 2)
void prep_kv(const float* __restrict__ K, const float* __restrict__ V,
             const int* __restrict__ Mask,
             ushort* __restrict__ Kp, ushort* __restrict__ Vtp,
             float* __restrict__ Mb)
{
  __shared__ ushort Vl[64 * 68];
  const int bid = blockIdx.x;      // bh*32 + kt
  const int tid = threadIdx.x;
  const float* Kg = K + (size_t)bid * 4096;
  const float* Vg = V + (size_t)bid * 4096;
  ushort* Kt = Kp + (size_t)bid * 4096;
  ushort* Vt = Vtp + (size_t)bid * 4096;

#pragma unroll
  for (int j = 0; j < 2; ++j) {
    int chunk = j * 256 + tid;
    int row = chunk >> 3, d8 = chunk & 7;
    const float* s = Kg + row * 64 + d8 * 8;
    float4 a = *(const float4*)s, b2 = *(const float4*)(s + 4);
    ushort8 o;
    o[0]=f2bf(a.x); o[1]=f2bf(a.y); o[2]=f2bf(a.z); o[3]=f2bf(a.w);
    o[4]=f2bf(b2.x);o[5]=f2bf(b2.y);o[6]=f2bf(b2.z);o[7]=f2bf(b2.w);
    *(ushort8*)(Kt + row * 64 + ((d8 * 8) ^ ((row & 7) << 3))) = o;

    const float* sv = Vg + row * 64 + d8 * 8;
    float4 va = *(const float4*)sv, vb2 = *(const float4*)(sv + 4);
    ushort4v w0, w1;
    w0[0]=f2bf(va.x); w0[1]=f2bf(va.y); w0[2]=f2bf(va.z); w0[3]=f2bf(va.w);
    w1[0]=f2bf(vb2.x);w1[1]=f2bf(vb2.y);w1[2]=f2bf(vb2.z);w1[3]=f2bf(vb2.w);
    *(ushort4v*)(&Vl[row * 68 + d8 * 8])     = w0;
    *(ushort4v*)(&Vl[row * 68 + d8 * 8 + 4]) = w1;
  }
  __syncthreads();
#pragma unroll
  for (int j = 0; j < 2; ++j) {
    int chunk = j * 256 + tid;
    int d = chunk >> 3, p8 = chunk & 7;
    ushort8 o;
#pragma unroll
    for (int e = 0; e < 8; ++e) {
      int pos = p8 * 8 + e;
      int c = pos >> 5, lgv = (pos >> 3) & 3, bb = (pos >> 2) & 1, aa = pos & 3;
      int kk = 32 * c + 16 * bb + 4 * lgv + aa;
      o[e] = Vl[kk * 68 + d];
    }
    *(ushort8*)(Vt + d * 64 + ((p8 * 8) ^ ((d & 7) << 3))) = o;
  }
  if ((((bid >> 5) & 15) == 0) && tid < 64) {
    int b = bid >> 9, kt = bid & 31;
    int idx = b * 2048 + kt * 64 + tid;
    Mb[idx] = (Mask[idx] != 0) ? 0.f : MASKBIAS;
  }
}

// ------- main attention: r16 rotated-PV pipeline, l on VALU (rebalanced) -------
__global__ __launch_bounds__(256, 2)
void attn_fwd20(const float* __restrict__ Q, const float* __restrict__ Mb,
                const ushort* __restrict__ Kp, const ushort* __restrict__ Vtp,
                float* __restrict__ O)
{
  __shared__ __align__(16) ushort Kb[2][4096];
  __shared__ __align__(16) ushort Vb[2][4096];

  const int tid  = threadIdx.x;
  const int wid  = tid >> 6;
  const int lane = tid & 63;
  const int lr   = lane & 15;
  const int lg   = lane >> 4;

  // XCD-aware mapping: 64 contiguous logical blocks per XCD -> 8 bh per XCD
  const int x   = blockIdx.x;           // 0..511
  const int lin = (x & 7) * 64 + (x >> 3);
  const int bh  = lin >> 3;             // 0..63
  const int qt  = lin & 7;              // 0..7
  const int b   = bh >> 4;

  // de-phase the 2 co-resident dispatch rounds by 16 KV-tiles
  const int phase = ((x >> 8) & 1) << 4;

  const float*  Qg    = Q + (size_t)bh * L_ * D_;
  float*        Og    = O + (size_t)bh * L_ * D_;
  const ushort* Kbase = Kp  + (size_t)bh * 131072;
  const ushort* Vbase = Vtp + (size_t)bh * 131072;
  const float*  Mbb   = Mb + (size_t)b * L_;

  const int qbase = qt * 256 + wid * 64;
  const float qscale = 0.125f * 1.4426950408889634f;  // scale * log2(e)

  // ---- Q fragments (scaled, bf16, persistent): 4 row-groups ----
  bf16x8 qf[4][2];
#pragma unroll
  for (int g = 0; g < 4; ++g)
#pragma unroll
    for (int c = 0; c < 2; ++c) {
      const float* src = Qg + (size_t)(qbase + g * 16 + lr) * D_ + c * 32 + lg * 8;
      float4 a = *(const float4*)src, b2 = *(const float4*)(src + 4);
      bf16x8 q;
      q[0]=f2bf(a.x*qscale);  q[1]=f2bf(a.y*qscale);  q[2]=f2bf(a.z*qscale);  q[3]=f2bf(a.w*qscale);
      q[4]=f2bf(b2.x*qscale); q[5]=f2bf(b2.y*qscale); q[6]=f2bf(b2.z*qscale); q[7]=f2bf(b2.w*qscale);
      qf[g][c] = q;
    }

  f32x4 o_acc[4][4];
#pragma unroll
  for (int g = 0; g < 4; ++g)
#pragma unroll
    for (int dt = 0; dt < 4; ++dt) o_acc[g][dt] = (f32x4){0.f,0.f,0.f,0.f};
  f32x4 l4[4];
#pragma unroll
  for (int g = 0; g < 4; ++g) l4[g] = (f32x4){0.f,0.f,0.f,0.f};

  // persistent pipeline registers: previous tile's packed P and V fragments
  union PKU { uint32_t u[8]; bf16x8 v[2]; };
  PKU    pkp[4];
  bf16x8 vbp[4][2];

  // ---- staging prologue: tile `phase` -> regs ----
  int kts = phase;
  ushort8 rk0, rk1, rv0, rv1;
  rk0 = *(const ushort8*)(Kbase + (size_t)kts * 4096 + wid * 1024 + lane * 8);
  rk1 = *(const ushort8*)(Kbase + (size_t)kts * 4096 + wid * 1024 + 512 + lane * 8);
  rv0 = *(const ushort8*)(Vbase + (size_t)kts * 4096 + wid * 1024 + lane * 8);
  rv1 = *(const ushort8*)(Vbase + (size_t)kts * 4096 + wid * 1024 + 512 + lane * 8);

  int cur = 0;
  for (int kt = 0; kt < NT_; ++kt) {
    // publish staged regs -> buf[cur]
    *(ushort8*)(&Kb[cur][wid * 1024 + lane * 8])       = rk0;
    *(ushort8*)(&Kb[cur][wid * 1024 + 512 + lane * 8]) = rk1;
    *(ushort8*)(&Vb[cur][wid * 1024 + lane * 8])       = rv0;
    *(ushort8*)(&Vb[cur][wid * 1024 + 512 + lane * 8]) = rv1;

    __syncthreads();

    // issue next tile's global loads (fly across full compute phase)
    const int knx = (kts + 1) & 31;
    {
      const ushort* Ks = Kbase + (size_t)knx * 4096;
      const ushort* Vs = Vbase + (size_t)knx * 4096;
      rk0 = *(const ushort8*)(Ks + wid * 1024 + lane * 8);
      rk1 = *(const ushort8*)(Ks + wid * 1024 + 512 + lane * 8);
      rv0 = *(const ushort8*)(Vs + wid * 1024 + lane * 8);
      rv1 = *(const ushort8*)(Vs + wid * 1024 + 512 + lane * 8);
    }

    // mask bias (global, L2-hot) — latency covered by PV(prev) below
    f32x4 bt[4];
#pragma unroll
    for (int t = 0; t < 4; ++t) bt[t] = *(const f32x4*)(Mbb + kts * 64 + 16 * t + 4 * lg);

    const ushort* Kc = Kb[cur];
    const ushort* Vc = Vb[cur];

    // K fragment ds_reads (latency covered by PV(prev))
    bf16x8 kf[4][2];
#pragma unroll
    for (int t = 0; t < 4; ++t)
#pragma unroll
      for (int c = 0; c < 2; ++c)
        kf[t][c] = *(const bf16x8*)(Kc + (16 * t + lr) * 64 + ((c * 32 + lg * 8) ^ ((lr & 7) << 3)));

    // ---- PV of PREVIOUS tile: all operands in registers ----
    if (kt > 0) {
      __builtin_amdgcn_s_setprio(1);
#pragma unroll
      for (int c = 0; c < 2; ++c)
#pragma unroll
        for (int dt = 0; dt < 4; ++dt)
#pragma unroll
          for (int g = 0; g < 4; ++g)
            o_acc[g][dt] = __builtin_amdgcn_mfma_f32_16x16x32_bf16(pkp[g].v[c], vbp[dt][c], o_acc[g][dt], 0, 0, 0);
      __builtin_amdgcn_s_setprio(0);
    }

    // V fragment ds_reads for THIS tile -> vbp (consumed next iter; huge slack)
#pragma unroll
    for (int dt = 0; dt < 4; ++dt)
#pragma unroll
      for (int c = 0; c < 2; ++c)
        vbp[dt][c] = *(const bf16x8*)(Vc + (16 * dt + lr) * 64 + ((c * 32 + lg * 8) ^ ((lr & 7) << 3)));

    // ---- QK^T (C-init=bias) -> exp2 -> l (VALU) -> pack into pkp ----
#pragma unroll
    for (int g = 0; g < 4; ++g) {
      f32x4 st[4];
      __builtin_amdgcn_s_setprio(1);
#pragma unroll
      for (int t = 0; t < 4; ++t)
        st[t] = __builtin_amdgcn_mfma_f32_16x16x32_bf16(kf[t][0], qf[g][0], bt[t], 0, 0, 0);
#pragma unroll
      for (int t = 0; t < 4; ++t)
        st[t] = __builtin_amdgcn_mfma_f32_16x16x32_bf16(kf[t][1], qf[g][1], st[t], 0, 0, 0);
      __builtin_amdgcn_s_setprio(0);

      f32x4 p0, p1, p2, p3;
#pragma unroll
      for (int r = 0; r < 4; ++r) {
        p0[r] = __builtin_amdgcn_exp2f(st[0][r]);
        p1[r] = __builtin_amdgcn_exp2f(st[1][r]);
        p2[r] = __builtin_amdgcn_exp2f(st[2][r]);
        p3[r] = __builtin_amdgcn_exp2f(st[3][r]);
      }
      l4[g] += (p0 + p1) + (p2 + p3);

      pkp[g].u[0] = pkbf(p0[0], p0[1]); pkp[g].u[1] = pkbf(p0[2], p0[3]);
      pkp[g].u[2] = pkbf(p1[0], p1[1]); pkp[g].u[3] = pkbf(p1[2], p1[3]);
      pkp[g].u[4] = pkbf(p2[0], p2[1]); pkp[g].u[5] = pkbf(p2[2], p2[3]);
      pkp[g].u[6] = pkbf(p3[0], p3[1]); pkp[g].u[7] = pkbf(p3[2], p3[3]);
    }

    kts = knx;
    cur ^= 1;
  }

  // ---- final PV for the last tile ----
  __builtin_amdgcn_s_setprio(1);
#pragma unroll
  for (int c = 0; c < 2; ++c)
#pragma unroll
    for (int dt = 0; dt < 4; ++dt)
#pragma unroll
      for (int g = 0; g < 4; ++g)
        o_acc[g][dt] = __builtin_amdgcn_mfma_f32_16x16x32_bf16(pkp[g].v[c], vbp[dt][c], o_acc[g][dt], 0, 0, 0);
  __builtin_amdgcn_s_setprio(0);

  // ---- epilogue: reduce l across lane-groups (r13-proven), O / l ----
#pragma unroll
  for (int g = 0; g < 4; ++g) {
    float lsum = (l4[g][0] + l4[g][1]) + (l4[g][2] + l4[g][3]);
    lsum += __shfl_xor(lsum, 16);
    lsum += __shfl_xor(lsum, 32);
    float linv[4];
#pragma unroll
    for (int r = 0; r < 4; ++r) {
      float lq = __shfl(lsum, 20 * lg + r);   // source lane has lr = 4lg+r
      linv[r] = 1.0f / lq;
    }
#pragma unroll
    for (int dt = 0; dt < 4; ++dt)
#pragma unroll
      for (int r = 0; r < 4; ++r) {
        int row = qbase + g * 16 + 4 * lg + r;
        Og[(size_t)row * D_ + dt * 16 + lr] = o_acc[g][dt][r] * linv[r];
      }
  }
}

extern "C" void kernel_launch(void* const* d_in, const int* in_sizes, int n_in,
                              void* d_out, int out_size, void* d_ws, size_t ws_size,
                              hipStream_t stream) {
  const float* Q = (const float*)d_in[0];
  const float* K = (const float*)d_in[1];
  const float* V = (const float*)d_in[2];
  const int*   M = (const int*)d_in[3];
  float*       O = (float*)d_out;

  const size_t elems = (size_t)BH_ * L_ * D_;   // 8,388,608
  ushort* Kp  = (ushort*)d_ws;
  ushort* Vtp = Kp + elems;
  float*  Mb  = (float*)(Vtp + elems);          // 4*2048 floats
  prep_kv<<<dim3(BH_ * NT_), dim3(256), 0, stream>>>(K, V, M, Kp, Vtp, Mb);
  attn_fwd20<<<dim3(512), dim3(256), 0, stream>>>(Q, Mb, Kp, Vtp, O);
}

// Round 22
// 87.643 us; speedup vs baseline: 1.2617x; 1.0484x over previous
//
#include <hip/hip_runtime.h>
#include <hip/hip_bf16.h>
#include <stdint.h>

#define B_    4
#define H_    16
#define L_    2048
#define D_    64
#define BH_   64
#define NT_   32
#define MASKBIAS (-1.4426950408889634e9f)   // -1e9 * log2(e), exp2-domain

typedef __attribute__((ext_vector_type(8))) short bf16x8;
typedef __attribute__((ext_vector_type(8))) unsigned short ushort8;
typedef __attribute__((ext_vector_type(4))) unsigned short ushort4v;
typedef __attribute__((ext_vector_type(4))) float f32x4;

__device__ __forceinline__ ushort f2bf(float f) {
  union { float f; uint32_t u; } x; x.f = f;
  uint32_t r = x.u + 0x7FFFu + ((x.u >> 16) & 1u);
  return (ushort)(r >> 16);
}

__device__ __forceinline__ uint32_t pkbf(float lo, float hi) {
  uint32_t r;
  asm("v_cvt_pk_bf16_f32 %0, %1, %2" : "=v"(r) : "v"(lo), "v"(hi));
  return r;
}

// ---------------- pre-pass: fp32 -> bf16, tiled + permuted + swizzled + mask bias ----------------
// Kp tile (bh,kt): elem(row,d) at row*64 + (d ^ ((row&7)<<3))
// Vtp tile: elem(d,pos) at d*64 + (pos ^ ((d&7)<<3)), holding V[k(pos)][d],
//   pos = 32c+8lg+4b+a  <->  k = 32c+16b+4lg+a  (MFMA A-frag slot order)
// Mb[b][k] = 0.0f (keep) or MASKBIAS (drop)
__global__ __launch_bounds__(256, 2)
void prep_kv(const float* __restrict__ K, const float* __restrict__ V,
             const int* __restrict__ Mask,
             ushort* __restrict__ Kp, ushort* __restrict__ Vtp,
             float* __restrict__ Mb)
{
  __shared__ ushort Vl[64 * 68];
  const int bid = blockIdx.x;      // bh*32 + kt
  const int tid = threadIdx.x;
  const float* Kg = K + (size_t)bid * 4096;
  const float* Vg = V + (size_t)bid * 4096;
  ushort* Kt = Kp + (size_t)bid * 4096;
  ushort* Vt = Vtp + (size_t)bid * 4096;

#pragma unroll
  for (int j = 0; j < 2; ++j) {
    int chunk = j * 256 + tid;
    int row = chunk >> 3, d8 = chunk & 7;
    const float* s = Kg + row * 64 + d8 * 8;
    float4 a = *(const float4*)s, b2 = *(const float4*)(s + 4);
    ushort8 o;
    o[0]=f2bf(a.x); o[1]=f2bf(a.y); o[2]=f2bf(a.z); o[3]=f2bf(a.w);
    o[4]=f2bf(b2.x);o[5]=f2bf(b2.y);o[6]=f2bf(b2.z);o[7]=f2bf(b2.w);
    *(ushort8*)(Kt + row * 64 + ((d8 * 8) ^ ((row & 7) << 3))) = o;

    const float* sv = Vg + row * 64 + d8 * 8;
    float4 va = *(const float4*)sv, vb2 = *(const float4*)(sv + 4);
    ushort4v w0, w1;
    w0[0]=f2bf(va.x); w0[1]=f2bf(va.y); w0[2]=f2bf(va.z); w0[3]=f2bf(va.w);
    w1[0]=f2bf(vb2.x);w1[1]=f2bf(vb2.y);w1[2]=f2bf(vb2.z);w1[3]=f2bf(vb2.w);
    *(ushort4v*)(&Vl[row * 68 + d8 * 8])     = w0;
    *(ushort4v*)(&Vl[row * 68 + d8 * 8 + 4]) = w1;
  }
  __syncthreads();
#pragma unroll
  for (int j = 0; j < 2; ++j) {
    int chunk = j * 256 + tid;
    int d = chunk >> 3, p8 = chunk & 7;
    ushort8 o;
#pragma unroll
    for (int e = 0; e < 8; ++e) {
      int pos = p8 * 8 + e;
      int c = pos >> 5, lgv = (pos >> 3) & 3, bb = (pos >> 2) & 1, aa = pos & 3;
      int kk = 32 * c + 16 * bb + 4 * lgv + aa;
      o[e] = Vl[kk * 68 + d];
    }
    *(ushort8*)(Vt + d * 64 + ((p8 * 8) ^ ((d & 7) << 3))) = o;
  }
  if ((((bid >> 5) & 15) == 0) && tid < 64) {
    int b = bid >> 9, kt = bid & 31;
    int idx = b * 2048 + kt * 64 + tid;
    Mb[idx] = (Mask[idx] != 0) ? 0.f : MASKBIAS;
  }
}

// ------- main attention: r12 geometry + PV rotated one iteration (reg-resident) -------
__global__ __launch_bounds__(256, 2)
void attn_fwd22(const float* __restrict__ Q, const float* __restrict__ Mb,
                const ushort* __restrict__ Kp, const ushort* __restrict__ Vtp,
                float* __restrict__ O)
{
  __shared__ __align__(16) ushort Kb[2][4096];
  __shared__ __align__(16) ushort Vb[2][4096];

  const int tid  = threadIdx.x;
  const int wid  = tid >> 6;
  const int lane = tid & 63;
  const int lr   = lane & 15;
  const int lg   = lane >> 4;

  // XCD-aware mapping: 64 contiguous logical blocks per XCD -> 8 bh per XCD
  const int x   = blockIdx.x;           // 0..511
  const int lin = (x & 7) * 64 + (x >> 3);
  const int bh  = lin >> 3;             // 0..63
  const int qt  = lin & 7;              // 0..7
  const int b   = bh >> 4;

  // de-phase the 2 co-resident dispatch rounds by 16 KV-tiles
  const int phase = ((x >> 8) & 1) << 4;

  const float*  Qg    = Q + (size_t)bh * L_ * D_;
  float*        Og    = O + (size_t)bh * L_ * D_;
  const ushort* Kbase = Kp  + (size_t)bh * 131072;
  const ushort* Vbase = Vtp + (size_t)bh * 131072;
  const float*  Mbb   = Mb + (size_t)b * L_;

  const int qbase = qt * 256 + wid * 64;
  const float qscale = 0.125f * 1.4426950408889634f;  // scale * log2(e)

  // ---- Q fragments (scaled, bf16, persistent): 4 row-groups ----
  bf16x8 qf[4][2];
#pragma unroll
  for (int g = 0; g < 4; ++g)
#pragma unroll
    for (int c = 0; c < 2; ++c) {
      const float* src = Qg + (size_t)(qbase + g * 16 + lr) * D_ + c * 32 + lg * 8;
      float4 a = *(const float4*)src, b2 = *(const float4*)(src + 4);
      bf16x8 q;
      q[0]=f2bf(a.x*qscale);  q[1]=f2bf(a.y*qscale);  q[2]=f2bf(a.z*qscale);  q[3]=f2bf(a.w*qscale);
      q[4]=f2bf(b2.x*qscale); q[5]=f2bf(b2.y*qscale); q[6]=f2bf(b2.z*qscale); q[7]=f2bf(b2.w*qscale);
      qf[g][c] = q;
    }

  f32x4 o_acc[4][4];
#pragma unroll
  for (int g = 0; g < 4; ++g)
#pragma unroll
    for (int dt = 0; dt < 4; ++dt) o_acc[g][dt] = (f32x4){0.f,0.f,0.f,0.f};
  f32x4 l_mf[4];
#pragma unroll
  for (int g = 0; g < 4; ++g) l_mf[g] = (f32x4){0.f,0.f,0.f,0.f};

  bf16x8 vone;
#pragma unroll
  for (int i = 0; i < 8; ++i) vone[i] = (short)0x3F80;  // bf16 1.0

  // persistent pipeline registers: previous tile's packed P and V fragments
  union PKU { uint32_t u[8]; bf16x8 v[2]; };
  PKU    pkp[4];
  bf16x8 vbp[4][2];

  // ---- staging prologue: tile `phase` -> regs ----
  int kts = phase;
  ushort8 rk0, rk1, rv0, rv1;
  rk0 = *(const ushort8*)(Kbase + (size_t)kts * 4096 + wid * 1024 + lane * 8);
  rk1 = *(const ushort8*)(Kbase + (size_t)kts * 4096 + wid * 1024 + 512 + lane * 8);
  rv0 = *(const ushort8*)(Vbase + (size_t)kts * 4096 + wid * 1024 + lane * 8);
  rv1 = *(const ushort8*)(Vbase + (size_t)kts * 4096 + wid * 1024 + 512 + lane * 8);

  int cur = 0;
  for (int kt = 0; kt < NT_; ++kt) {
    // publish staged regs -> buf[cur]
    *(ushort8*)(&Kb[cur][wid * 1024 + lane * 8])       = rk0;
    *(ushort8*)(&Kb[cur][wid * 1024 + 512 + lane * 8]) = rk1;
    *(ushort8*)(&Vb[cur][wid * 1024 + lane * 8])       = rv0;
    *(ushort8*)(&Vb[cur][wid * 1024 + 512 + lane * 8]) = rv1;

    __syncthreads();

    // issue next tile's global loads (fly across full compute phase)
    const int knx = (kts + 1) & 31;
    {
      const ushort* Ks = Kbase + (size_t)knx * 4096;
      const ushort* Vs = Vbase + (size_t)knx * 4096;
      rk0 = *(const ushort8*)(Ks + wid * 1024 + lane * 8);
      rk1 = *(const ushort8*)(Ks + wid * 1024 + 512 + lane * 8);
      rv0 = *(const ushort8*)(Vs + wid * 1024 + lane * 8);
      rv1 = *(const ushort8*)(Vs + wid * 1024 + 512 + lane * 8);
    }

    // mask bias (global, L2-hot) — latency covered by PV(prev) below
    f32x4 bt[4];
#pragma unroll
    for (int t = 0; t < 4; ++t) bt[t] = *(const f32x4*)(Mbb + kts * 64 + 16 * t + 4 * lg);

    const ushort* Kc = Kb[cur];
    const ushort* Vc = Vb[cur];

    // K fragment ds_reads (latency covered by PV(prev))
    bf16x8 kf[4][2];
#pragma unroll
    for (int t = 0; t < 4; ++t)
#pragma unroll
      for (int c = 0; c < 2; ++c)
        kf[t][c] = *(const bf16x8*)(Kc + (16 * t + lr) * 64 + ((c * 32 + lg * 8) ^ ((lr & 7) << 3)));

    // ---- PV + l of PREVIOUS tile: all operands in registers ----
    if (kt > 0) {
      __builtin_amdgcn_s_setprio(1);
#pragma unroll
      for (int g = 0; g < 4; ++g) {
        l_mf[g] = __builtin_amdgcn_mfma_f32_16x16x32_bf16(pkp[g].v[0], vone, l_mf[g], 0, 0, 0);
        l_mf[g] = __builtin_amdgcn_mfma_f32_16x16x32_bf16(pkp[g].v[1], vone, l_mf[g], 0, 0, 0);
      }
#pragma unroll
      for (int c = 0; c < 2; ++c)
#pragma unroll
        for (int dt = 0; dt < 4; ++dt)
#pragma unroll
          for (int g = 0; g < 4; ++g)
            o_acc[g][dt] = __builtin_amdgcn_mfma_f32_16x16x32_bf16(pkp[g].v[c], vbp[dt][c], o_acc[g][dt], 0, 0, 0);
      __builtin_amdgcn_s_setprio(0);
    }

    // V fragment ds_reads for THIS tile -> vbp (consumed next iter; huge slack)
#pragma unroll
    for (int dt = 0; dt < 4; ++dt)
#pragma unroll
      for (int c = 0; c < 2; ++c)
        vbp[dt][c] = *(const bf16x8*)(Vc + (16 * dt + lr) * 64 + ((c * 32 + lg * 8) ^ ((lr & 7) << 3)));

    // ---- QK^T (C-init=bias) -> exp2 -> pack into pkp (pkp free after PV above) ----
#pragma unroll
    for (int g = 0; g < 4; ++g) {
      f32x4 st[4];
      __builtin_amdgcn_s_setprio(1);
#pragma unroll
      for (int t = 0; t < 4; ++t)
        st[t] = __builtin_amdgcn_mfma_f32_16x16x32_bf16(kf[t][0], qf[g][0], bt[t], 0, 0, 0);
#pragma unroll
      for (int t = 0; t < 4; ++t)
        st[t] = __builtin_amdgcn_mfma_f32_16x16x32_bf16(kf[t][1], qf[g][1], st[t], 0, 0, 0);
      __builtin_amdgcn_s_setprio(0);

      f32x4 p0, p1, p2, p3;
#pragma unroll
      for (int r = 0; r < 4; ++r) {
        p0[r] = __builtin_amdgcn_exp2f(st[0][r]);
        p1[r] = __builtin_amdgcn_exp2f(st[1][r]);
        p2[r] = __builtin_amdgcn_exp2f(st[2][r]);
        p3[r] = __builtin_amdgcn_exp2f(st[3][r]);
      }
      pkp[g].u[0] = pkbf(p0[0], p0[1]); pkp[g].u[1] = pkbf(p0[2], p0[3]);
      pkp[g].u[2] = pkbf(p1[0], p1[1]); pkp[g].u[3] = pkbf(p1[2], p1[3]);
      pkp[g].u[4] = pkbf(p2[0], p2[1]); pkp[g].u[5] = pkbf(p2[2], p2[3]);
      pkp[g].u[6] = pkbf(p3[0], p3[1]); pkp[g].u[7] = pkbf(p3[2], p3[3]);
    }

    kts = knx;
    cur ^= 1;
  }

  // ---- final PV + l for the last tile ----
  __builtin_amdgcn_s_setprio(1);
#pragma unroll
  for (int g = 0; g < 4; ++g) {
    l_mf[g] = __builtin_amdgcn_mfma_f32_16x16x32_bf16(pkp[g].v[0], vone, l_mf[g], 0, 0, 0);
    l_mf[g] = __builtin_amdgcn_mfma_f32_16x16x32_bf16(pkp[g].v[1], vone, l_mf[g], 0, 0, 0);
  }
#pragma unroll
  for (int c = 0; c < 2; ++c)
#pragma unroll
    for (int dt = 0; dt < 4; ++dt)
#pragma unroll
      for (int g = 0; g < 4; ++g)
        o_acc[g][dt] = __builtin_amdgcn_mfma_f32_16x16x32_bf16(pkp[g].v[c], vbp[dt][c], o_acc[g][dt], 0, 0, 0);
  __builtin_amdgcn_s_setprio(0);

  // ---- epilogue: l_mf[g][r] already per-q (lane-replicated) ----
#pragma unroll
  for (int g = 0; g < 4; ++g) {
    float linv[4];
#pragma unroll
    for (int r = 0; r < 4; ++r) linv[r] = 1.0f / l_mf[g][r];
#pragma unroll
    for (int dt = 0; dt < 4; ++dt)
#pragma unroll
      for (int r = 0; r < 4; ++r) {
        int row = qbase + g * 16 + 4 * lg + r;
        Og[(size_t)row * D_ + dt * 16 + lr] = o_acc[g][dt][r] * linv[r];
      }
  }
}

extern "C" void kernel_launch(void* const* d_in, const int* in_sizes, int n_in,
                              void* d_out, int out_size, void* d_ws, size_t ws_size,
                              hipStream_t stream) {
  const float* Q = (const float*)d_in[0];
  const float* K = (const float*)d_in[1];
  const float* V = (const float*)d_in[2];
  const int*   M = (const int*)d_in[3];
  float*       O = (float*)d_out;

  const size_t elems = (size_t)BH_ * L_ * D_;   // 8,388,608
  ushort* Kp  = (ushort*)d_ws;
  ushort* Vtp = Kp + elems;
  float*  Mb  = (float*)(Vtp + elems);          // 4*2048 floats
  prep_kv<<<dim3(BH_ * NT_), dim3(256), 0, stream>>>(K, V, M, Kp, Vtp, Mb);
  attn_fwd22<<<dim3(512), dim3(256), 0, stream>>>(Q, Mb, Kp, Vtp, O);
}